// Round 1
// baseline (2290.779 us; speedup 1.0000x reference)
//
#include <hip/hip_runtime.h>

#define N_NODES 50000

// ---------------- degree / dinv ----------------
__global__ __launch_bounds__(256) void deg_init(int* __restrict__ deg, int n) {
    int i = blockIdx.x * 256 + threadIdx.x;
    if (i < n) deg[i] = 1;  // self-loop
}

__global__ __launch_bounds__(256) void deg_count(const int* __restrict__ dst,
                                                 int* __restrict__ deg, int E) {
    int i = blockIdx.x * 256 + threadIdx.x;
    if (i < E) atomicAdd(&deg[dst[i]], 1);
}

__global__ __launch_bounds__(256) void dinv_kernel(const int* __restrict__ deg,
                                                   float* __restrict__ dinv, int n) {
    int i = blockIdx.x * 256 + threadIdx.x;
    if (i < n) dinv[i] = rsqrtf((float)deg[i]);
}

// ---------------- fp32 tiled GEMM with row-scale epilogue ----------------
// C[r, c] = dinv[r] * sum_k A[r,k] * B[k,c]
// BM=64, BN=64, BK=16, 256 threads, 4x4 micro-tile per thread.
template <int BK>
__global__ __launch_bounds__(256) void gemm_rowscale(const float* __restrict__ A,
                                                     const float* __restrict__ B,
                                                     const float* __restrict__ dinv,
                                                     float* __restrict__ C,
                                                     int N, int K, int M) {
    const int BM = 64, BN = 64, TM = 4, TN = 4;
    __shared__ float As[BM * (BK + 1)];  // +1 pad: kills 4-way bank conflict on a[i] loads
    __shared__ float Bs[BK * BN];

    const int row0 = blockIdx.y * BM;
    const int col0 = blockIdx.x * BN;
    const int tid = threadIdx.x;
    const int tr = tid >> 4;   // 0..15
    const int tc = tid & 15;   // 0..15

    float acc[TM][TN] = {};

    for (int k0 = 0; k0 < K; k0 += BK) {
        // stage A tile (BM x BK), guard rows
        for (int t = tid; t < BM * BK; t += 256) {
            int r = t / BK, c = t % BK;
            int gr = row0 + r;
            As[r * (BK + 1) + c] = (gr < N) ? A[(long long)gr * K + k0 + c] : 0.0f;
        }
        // stage B tile (BK x BN) — coalesced over 64-wide rows
        for (int t = tid; t < BK * BN; t += 256) {
            int r = t / BN, c = t % BN;
            Bs[t] = B[(k0 + r) * M + col0 + c];
        }
        __syncthreads();

#pragma unroll
        for (int kk = 0; kk < BK; kk++) {
            float a[TM], b[TN];
#pragma unroll
            for (int i = 0; i < TM; i++) a[i] = As[(tr * TM + i) * (BK + 1) + kk];
#pragma unroll
            for (int j = 0; j < TN; j++) b[j] = Bs[kk * BN + tc * TN + j];
#pragma unroll
            for (int i = 0; i < TM; i++)
#pragma unroll
                for (int j = 0; j < TN; j++) acc[i][j] += a[i] * b[j];
        }
        __syncthreads();
    }

#pragma unroll
    for (int i = 0; i < TM; i++) {
        int gr = row0 + tr * TM + i;
        if (gr < N) {
            float s = dinv[gr];
#pragma unroll
            for (int j = 0; j < TN; j++)
                C[(long long)gr * M + col0 + tc * TN + j] = s * acc[i][j];
        }
    }
}

// ---------------- edge scatter-add ----------------
// thread handles (edge, 4-feature chunk): idx = e * (M/4) + q
__global__ __launch_bounds__(256) void scatter_edges(const int* __restrict__ src,
                                                     const int* __restrict__ dst,
                                                     const float* __restrict__ hn,
                                                     float* __restrict__ agg,
                                                     int total, int logMq, int M) {
    int idx = blockIdx.x * 256 + threadIdx.x;
    if (idx >= total) return;
    int e = idx >> logMq;
    int q = idx & ((1 << logMq) - 1);
    int s = src[e];
    int d = dst[e];
    const float4 v = *(const float4*)(hn + s * M + q * 4);
    float* p = agg + d * M + q * 4;
    unsafeAtomicAdd(p + 0, v.x);
    unsafeAtomicAdd(p + 1, v.y);
    unsafeAtomicAdd(p + 2, v.z);
    unsafeAtomicAdd(p + 3, v.w);
}

// ---------------- epilogue: out = [relu](dinv[v] * (agg + hn_self) + bias) ----------------
template <bool RELU>
__global__ __launch_bounds__(256) void finalize(const float* __restrict__ hn,
                                                const float* __restrict__ agg,
                                                const float* __restrict__ dinv,
                                                const float* __restrict__ bias,
                                                float* __restrict__ outp,
                                                int total, int logM) {
    int i = blockIdx.x * 256 + threadIdx.x;
    if (i >= total) return;
    int v = i >> logM;
    int j = i & ((1 << logM) - 1);
    float val = dinv[v] * (agg[i] + hn[i]) + bias[j];
    if (RELU) val = fmaxf(val, 0.0f);
    outp[i] = val;
}

extern "C" void kernel_launch(void* const* d_in, const int* in_sizes, int n_in,
                              void* d_out, int out_size, void* d_ws, size_t ws_size,
                              hipStream_t stream) {
    const float* x  = (const float*)d_in[0];
    const int*   ei = (const int*)d_in[1];   // harness delivers integer inputs as int32
    const float* W1 = (const float*)d_in[2];
    const float* b1 = (const float*)d_in[3];
    const float* W2 = (const float*)d_in[4];
    const float* b2 = (const float*)d_in[5];

    const int N = N_NODES;
    const int E = in_sizes[1] / 2;
    const int* src = ei;
    const int* dst = ei + E;

    // workspace carve-up (256B aligned regions)
    char* ws = (char*)d_ws;
    size_t off = 0;
    auto carve = [&](size_t bytes) {
        char* p = ws + off;
        off += (bytes + 255) & ~(size_t)255;
        return p;
    };
    int*   deg  = (int*)  carve((size_t)N * 4);
    float* dinv = (float*)carve((size_t)N * 4);
    float* hn1  = (float*)carve((size_t)N * 128 * 4);  // reused: hn2 (first N*64) + agg2 (second N*64)
    float* agg1 = (float*)carve((size_t)N * 128 * 4);  // after finalize1 holds h1
    float* hn2  = hn1;            // hn1 is dead after finalize1
    float* agg2 = hn1 + (size_t)N * 64;
    float* h1   = agg1;

    // 1) degrees + dinv (shared by both layers)
    deg_init<<<(N + 255) / 256, 256, 0, stream>>>(deg, N);
    deg_count<<<(E + 255) / 256, 256, 0, stream>>>(dst, deg, E);
    dinv_kernel<<<(N + 255) / 256, 256, 0, stream>>>(deg, dinv, N);

    // 2) layer 1: hn1 = dinv * (x @ W1)
    {
        dim3 grid(128 / 64, (N + 63) / 64);
        gemm_rowscale<16><<<grid, 256, 0, stream>>>(x, W1, dinv, hn1, N, 256, 128);
    }
    hipMemsetAsync(agg1, 0, (size_t)N * 128 * 4, stream);
    {
        int total = E * 32;  // E * (128/4)
        scatter_edges<<<(total + 255) / 256, 256, 0, stream>>>(src, dst, hn1, agg1, total, 5, 128);
    }
    {
        int total = N * 128;
        finalize<true><<<(total + 255) / 256, 256, 0, stream>>>(hn1, agg1, dinv, b1, h1, total, 7);
    }

    // 3) layer 2: hn2 = dinv * (h1 @ W2)
    {
        dim3 grid(64 / 64, (N + 63) / 64);
        gemm_rowscale<16><<<grid, 256, 0, stream>>>(h1, W2, dinv, hn2, N, 128, 64);
    }
    hipMemsetAsync(agg2, 0, (size_t)N * 64 * 4, stream);
    {
        int total = E * 16;  // E * (64/4)
        scatter_edges<<<(total + 255) / 256, 256, 0, stream>>>(src, dst, hn2, agg2, total, 4, 64);
    }
    {
        int total = N * 64;
        finalize<false><<<(total + 255) / 256, 256, 0, stream>>>(hn2, agg2, dinv, b2, (float*)d_out, total, 6);
    }
}

// Round 2
// 380.584 us; speedup vs baseline: 6.0191x; 6.0191x over previous
//
#include <hip/hip_runtime.h>

#define N_NODES 50000

// ============ CSR build: histogram -> scan -> fill ============

__global__ __launch_bounds__(256) void hist_count(const int* __restrict__ dst,
                                                  int* __restrict__ hist, int E) {
    int i = blockIdx.x * 256 + threadIdx.x;
    if (i < E) atomicAdd(&hist[dst[i]], 1);
}

// block-wise exclusive scan (256/block), emits per-block sums
__global__ __launch_bounds__(256) void scan1(const int* __restrict__ hist,
                                             int* __restrict__ excl,
                                             int* __restrict__ blocksums, int n) {
    __shared__ int sh[256];
    int i = blockIdx.x * 256 + threadIdx.x;
    int v = (i < n) ? hist[i] : 0;
    sh[threadIdx.x] = v;
    __syncthreads();
    for (int off = 1; off < 256; off <<= 1) {
        int t = (threadIdx.x >= off) ? sh[threadIdx.x - off] : 0;
        __syncthreads();
        sh[threadIdx.x] += t;
        __syncthreads();
    }
    if (i < n) excl[i] = sh[threadIdx.x] - v;
    if (threadIdx.x == 255) blocksums[blockIdx.x] = sh[255];
}

// single-block exclusive scan of block sums (nb <= 256)
__global__ __launch_bounds__(256) void scan2(int* __restrict__ blocksums, int nb) {
    __shared__ int sh[256];
    int v = (threadIdx.x < nb) ? blocksums[threadIdx.x] : 0;
    sh[threadIdx.x] = v;
    __syncthreads();
    for (int off = 1; off < 256; off <<= 1) {
        int t = (threadIdx.x >= off) ? sh[threadIdx.x - off] : 0;
        __syncthreads();
        sh[threadIdx.x] += t;
        __syncthreads();
    }
    if (threadIdx.x < nb) blocksums[threadIdx.x] = sh[threadIdx.x] - v;
}

// add block offsets; produce rowptr + cursor + dinv
__global__ __launch_bounds__(256) void scan3(const int* __restrict__ excl,
                                             const int* __restrict__ blocksums,
                                             const int* __restrict__ hist,
                                             int* __restrict__ rowptr,
                                             int* __restrict__ cursor,
                                             float* __restrict__ dinv,
                                             int n, int E) {
    int i = blockIdx.x * 256 + threadIdx.x;
    if (i < n) {
        int r = excl[i] + blocksums[blockIdx.x];
        rowptr[i] = r;
        cursor[i] = r;
        dinv[i] = rsqrtf((float)(hist[i] + 1));  // +1 self-loop
    }
    if (i == 0) rowptr[n] = E;
}

__global__ __launch_bounds__(256) void csr_fill(const int* __restrict__ src,
                                                const int* __restrict__ dst,
                                                int* __restrict__ cursor,
                                                int* __restrict__ csr_src, int E) {
    int e = blockIdx.x * 256 + threadIdx.x;
    if (e < E) {
        int pos = atomicAdd(&cursor[dst[e]], 1);
        csr_src[pos] = src[e];
    }
}

// ============ fp32 tiled GEMM with row-scale epilogue ============
// C[r, c] = dinv[r] * sum_k A[r,k] * B[k,c]
template <int BK>
__global__ __launch_bounds__(256) void gemm_rowscale(const float* __restrict__ A,
                                                     const float* __restrict__ B,
                                                     const float* __restrict__ dinv,
                                                     float* __restrict__ C,
                                                     int N, int K, int M) {
    const int BM = 64, BN = 64, TM = 4, TN = 4;
    __shared__ float As[BM * (BK + 1)];
    __shared__ float Bs[BK * BN];

    const int row0 = blockIdx.y * BM;
    const int col0 = blockIdx.x * BN;
    const int tid = threadIdx.x;
    const int tr = tid >> 4;
    const int tc = tid & 15;

    float acc[TM][TN] = {};

    for (int k0 = 0; k0 < K; k0 += BK) {
        for (int t = tid; t < BM * BK; t += 256) {
            int r = t / BK, c = t % BK;
            int gr = row0 + r;
            As[r * (BK + 1) + c] = (gr < N) ? A[(long long)gr * K + k0 + c] : 0.0f;
        }
        for (int t = tid; t < BK * BN; t += 256) {
            int r = t / BN, c = t % BN;
            Bs[t] = B[(k0 + r) * M + col0 + c];
        }
        __syncthreads();

#pragma unroll
        for (int kk = 0; kk < BK; kk++) {
            float a[TM], b[TN];
#pragma unroll
            for (int i = 0; i < TM; i++) a[i] = As[(tr * TM + i) * (BK + 1) + kk];
#pragma unroll
            for (int j = 0; j < TN; j++) b[j] = Bs[kk * BN + tc * TN + j];
#pragma unroll
            for (int i = 0; i < TM; i++)
#pragma unroll
                for (int j = 0; j < TN; j++) acc[i][j] += a[i] * b[j];
        }
        __syncthreads();
    }

#pragma unroll
    for (int i = 0; i < TM; i++) {
        int gr = row0 + tr * TM + i;
        if (gr < N) {
            float s = dinv[gr];
#pragma unroll
            for (int j = 0; j < TN; j++)
                C[(long long)gr * M + col0 + tc * TN + j] = s * acc[i][j];
        }
    }
}

// ============ fused gather-aggregate + epilogue ============
// out[v,:] = [relu]( dinv[v] * (sum_{e in in(v)} hn[src_e,:] + hn[v,:]) + bias )
// MQ = M/4 float4 lanes per node; GPB = 256/MQ node-groups per block.
template <bool RELU, int MQ>
__global__ __launch_bounds__(256) void gather_agg(const float4* __restrict__ hnv,
                                                  const int* __restrict__ rowptr,
                                                  const int* __restrict__ csr_src,
                                                  const float* __restrict__ dinv,
                                                  const float4* __restrict__ biasv,
                                                  float4* __restrict__ outv, int n) {
    const int GPB = 256 / MQ;
    int g = blockIdx.x * GPB + threadIdx.x / MQ;   // node
    int j = threadIdx.x % MQ;                      // float4 lane within row
    if (g >= n) return;

    float4 acc = hnv[(size_t)g * MQ + j];          // self-loop term
    int e = rowptr[g];
    const int end = rowptr[g + 1];
    for (; e + 1 < end; e += 2) {
        int s0 = csr_src[e];
        int s1 = csr_src[e + 1];
        float4 a = hnv[(size_t)s0 * MQ + j];
        float4 b = hnv[(size_t)s1 * MQ + j];
        acc.x += a.x + b.x;
        acc.y += a.y + b.y;
        acc.z += a.z + b.z;
        acc.w += a.w + b.w;
    }
    if (e < end) {
        int s0 = csr_src[e];
        float4 a = hnv[(size_t)s0 * MQ + j];
        acc.x += a.x; acc.y += a.y; acc.z += a.z; acc.w += a.w;
    }

    float s = dinv[g];
    float4 bv = biasv[j];
    float4 r;
    r.x = s * acc.x + bv.x;
    r.y = s * acc.y + bv.y;
    r.z = s * acc.z + bv.z;
    r.w = s * acc.w + bv.w;
    if (RELU) {
        r.x = fmaxf(r.x, 0.0f); r.y = fmaxf(r.y, 0.0f);
        r.z = fmaxf(r.z, 0.0f); r.w = fmaxf(r.w, 0.0f);
    }
    outv[(size_t)g * MQ + j] = r;
}

extern "C" void kernel_launch(void* const* d_in, const int* in_sizes, int n_in,
                              void* d_out, int out_size, void* d_ws, size_t ws_size,
                              hipStream_t stream) {
    const float* x  = (const float*)d_in[0];
    const int*   ei = (const int*)d_in[1];
    const float* W1 = (const float*)d_in[2];
    const float* b1 = (const float*)d_in[3];
    const float* W2 = (const float*)d_in[4];
    const float* b2 = (const float*)d_in[5];

    const int N = N_NODES;
    const int E = in_sizes[1] / 2;
    const int* src = ei;
    const int* dst = ei + E;

    char* ws = (char*)d_ws;
    size_t off = 0;
    auto carve = [&](size_t bytes) {
        char* p = ws + off;
        off += (bytes + 255) & ~(size_t)255;
        return p;
    };
    int*   hist    = (int*)  carve((size_t)N * 4);
    int*   excl    = (int*)  carve((size_t)N * 4);
    int*   bsums   = (int*)  carve(256 * 4);
    int*   rowptr  = (int*)  carve((size_t)(N + 1) * 4);
    int*   cursor  = (int*)  carve((size_t)N * 4);
    int*   csr_src = (int*)  carve((size_t)E * 4);
    float* dinv    = (float*)carve((size_t)N * 4);
    float* hn1     = (float*)carve((size_t)N * 128 * 4);
    float* h1      = (float*)carve((size_t)N * 128 * 4);
    float* hn2     = hn1;  // hn1 dead after gather1 writes h1

    const int NB = (N + 255) / 256;  // 196

    // ---- CSR build + dinv ----
    hipMemsetAsync(hist, 0, (size_t)N * 4, stream);
    hist_count<<<(E + 255) / 256, 256, 0, stream>>>(dst, hist, E);
    scan1<<<NB, 256, 0, stream>>>(hist, excl, bsums, N);
    scan2<<<1, 256, 0, stream>>>(bsums, NB);
    scan3<<<NB, 256, 0, stream>>>(excl, bsums, hist, rowptr, cursor, dinv, N, E);
    csr_fill<<<(E + 255) / 256, 256, 0, stream>>>(src, dst, cursor, csr_src, E);

    // ---- layer 1: hn1 = dinv * (x @ W1); h1 = relu(gather + self + b1) ----
    {
        dim3 grid(128 / 64, (N + 63) / 64);
        gemm_rowscale<16><<<grid, 256, 0, stream>>>(x, W1, dinv, hn1, N, 256, 128);
    }
    {
        const int GPB = 256 / 32;  // 8 nodes/block
        gather_agg<true, 32><<<(N + GPB - 1) / GPB, 256, 0, stream>>>(
            (const float4*)hn1, rowptr, csr_src, dinv, (const float4*)b1,
            (float4*)h1, N);
    }

    // ---- layer 2: hn2 = dinv * (h1 @ W2); out = gather + self + b2 ----
    {
        dim3 grid(64 / 64, (N + 63) / 64);
        gemm_rowscale<16><<<grid, 256, 0, stream>>>(h1, W2, dinv, hn2, N, 128, 64);
    }
    {
        const int GPB = 256 / 16;  // 16 nodes/block
        gather_agg<false, 16><<<(N + GPB - 1) / GPB, 256, 0, stream>>>(
            (const float4*)hn2, rowptr, csr_src, dinv, (const float4*)b2,
            (float4*)d_out, N);
    }
}

// Round 3
// 360.100 us; speedup vs baseline: 6.3615x; 1.0569x over previous
//
#include <hip/hip_runtime.h>

#define N_NODES 50000

typedef short bf16x8 __attribute__((ext_vector_type(8)));
typedef float f32x4 __attribute__((ext_vector_type(4)));

__device__ inline unsigned short f2bf(float f) {
    union { float f; unsigned u; } v; v.f = f;
    unsigned u = v.u;
    unsigned lsb = (u >> 16) & 1u;
    u += 0x7fffu + lsb;  // round-to-nearest-even
    return (unsigned short)(u >> 16);
}

__device__ inline float bf2f(unsigned short h) {
    union { unsigned u; float f; } v; v.u = ((unsigned)h) << 16;
    return v.f;
}

// ============ CSR build: histogram -> scan -> fill ============

__global__ __launch_bounds__(256) void hist_count(const int* __restrict__ dst,
                                                  int* __restrict__ hist, int E) {
    int i = blockIdx.x * 256 + threadIdx.x;
    if (i < E) atomicAdd(&hist[dst[i]], 1);
}

__global__ __launch_bounds__(256) void scan1(const int* __restrict__ hist,
                                             int* __restrict__ excl,
                                             int* __restrict__ blocksums, int n) {
    __shared__ int sh[256];
    int i = blockIdx.x * 256 + threadIdx.x;
    int v = (i < n) ? hist[i] : 0;
    sh[threadIdx.x] = v;
    __syncthreads();
    for (int off = 1; off < 256; off <<= 1) {
        int t = (threadIdx.x >= off) ? sh[threadIdx.x - off] : 0;
        __syncthreads();
        sh[threadIdx.x] += t;
        __syncthreads();
    }
    if (i < n) excl[i] = sh[threadIdx.x] - v;
    if (threadIdx.x == 255) blocksums[blockIdx.x] = sh[255];
}

__global__ __launch_bounds__(256) void scan2(int* __restrict__ blocksums, int nb) {
    __shared__ int sh[256];
    int v = (threadIdx.x < nb) ? blocksums[threadIdx.x] : 0;
    sh[threadIdx.x] = v;
    __syncthreads();
    for (int off = 1; off < 256; off <<= 1) {
        int t = (threadIdx.x >= off) ? sh[threadIdx.x - off] : 0;
        __syncthreads();
        sh[threadIdx.x] += t;
        __syncthreads();
    }
    if (threadIdx.x < nb) blocksums[threadIdx.x] = sh[threadIdx.x] - v;
}

__global__ __launch_bounds__(256) void scan3(const int* __restrict__ excl,
                                             const int* __restrict__ blocksums,
                                             const int* __restrict__ hist,
                                             int* __restrict__ rowptr,
                                             int* __restrict__ cursor,
                                             float* __restrict__ dinv,
                                             int n, int E) {
    int i = blockIdx.x * 256 + threadIdx.x;
    if (i < n) {
        int r = excl[i] + blocksums[blockIdx.x];
        rowptr[i] = r;
        cursor[i] = r;
        dinv[i] = rsqrtf((float)(hist[i] + 1));  // +1 self-loop
    }
    if (i == 0) rowptr[n] = E;
}

__global__ __launch_bounds__(256) void csr_fill(const int* __restrict__ src,
                                                const int* __restrict__ dst,
                                                int* __restrict__ cursor,
                                                int* __restrict__ csr_src, int E) {
    int e = blockIdx.x * 256 + threadIdx.x;
    if (e < E) {
        int pos = atomicAdd(&cursor[dst[e]], 1);
        csr_src[pos] = src[e];
    }
}

// ============ W transpose + hi/lo bf16 split ============
// W [K,M] fp32 -> Wt_hi/lo [M,K] bf16-bits
__global__ __launch_bounds__(256) void wsplit(const float* __restrict__ W,
                                              unsigned short* __restrict__ Th,
                                              unsigned short* __restrict__ Tl,
                                              int K, int logM) {
    int i = blockIdx.x * 256 + threadIdx.x;
    int M = 1 << logM;
    if (i >= K * M) return;
    int k = i >> logM;
    int n = i & (M - 1);
    float v = W[i];
    unsigned short h = f2bf(v);
    float r = v - bf2f(h);
    Th[(size_t)n * K + k] = h;
    Tl[(size_t)n * K + k] = f2bf(r);
}

// ============ MFMA GEMM with 3-term bf16 split (fp32-accurate) ============
// C[r,c] = dinv[r] * sum_k A[r,k]*B[k,c];  Bt = B^T pre-split into hi/lo.
// Block: 256 thr = 4 waves; wave handles 16 rows x M cols. Grid: ceil(N/64).
template <int K, int M>
__global__ __launch_bounds__(256) void gemm_mfma_split(const float* __restrict__ A,
                                                       const unsigned short* __restrict__ Bth,
                                                       const unsigned short* __restrict__ Btl,
                                                       const float* __restrict__ dinv,
                                                       float* __restrict__ C, int N) {
    const int CT = M / 16;   // col tiles
    const int KS = K / 32;   // k steps
    const int wave = threadIdx.x >> 6;
    const int lane = threadIdx.x & 63;
    const int n16 = lane & 15;
    const int quad = lane >> 4;

    const int row = blockIdx.x * 64 + wave * 16 + n16;  // A row this lane loads
    const int arow = (row < N) ? row : (N - 1);
    const float* ap = A + (size_t)arow * K;

    f32x4 acc[CT] = {};

    for (int ks = 0; ks < KS; ks++) {
        const int k0 = ks * 32 + quad * 8;
        float4 a01 = *(const float4*)(ap + k0);
        float4 a23 = *(const float4*)(ap + k0 + 4);
        float av[8] = {a01.x, a01.y, a01.z, a01.w, a23.x, a23.y, a23.z, a23.w};
        bf16x8 a_hi, a_lo;
#pragma unroll
        for (int j = 0; j < 8; j++) {
            unsigned short h = f2bf(av[j]);
            float r = av[j] - bf2f(h);
            a_hi[j] = (short)h;
            a_lo[j] = (short)f2bf(r);
        }
#pragma unroll
        for (int c = 0; c < CT; c++) {
            const size_t boff = (size_t)(c * 16 + n16) * K + k0;
            bf16x8 b_hi = *(const bf16x8*)(Bth + boff);
            bf16x8 b_lo = *(const bf16x8*)(Btl + boff);
            acc[c] = __builtin_amdgcn_mfma_f32_16x16x32_bf16(a_hi, b_hi, acc[c], 0, 0, 0);
            acc[c] = __builtin_amdgcn_mfma_f32_16x16x32_bf16(a_hi, b_lo, acc[c], 0, 0, 0);
            acc[c] = __builtin_amdgcn_mfma_f32_16x16x32_bf16(a_lo, b_hi, acc[c], 0, 0, 0);
        }
    }

    // D mapping: col = lane&15 (tile-local), row = quad*4 + reg
    const int orow_base = blockIdx.x * 64 + wave * 16 + quad * 4;
#pragma unroll
    for (int r = 0; r < 4; r++) {
        int orow = orow_base + r;
        if (orow < N) {
            float s = dinv[orow];
#pragma unroll
            for (int c = 0; c < CT; c++)
                C[(size_t)orow * M + c * 16 + n16] = s * acc[c][r];
        }
    }
}

// ============ fused gather-aggregate + epilogue ============
template <bool RELU, int MQ>
__global__ __launch_bounds__(256) void gather_agg(const float4* __restrict__ hnv,
                                                  const int* __restrict__ rowptr,
                                                  const int* __restrict__ csr_src,
                                                  const float* __restrict__ dinv,
                                                  const float4* __restrict__ biasv,
                                                  float4* __restrict__ outv, int n) {
    const int GPB = 256 / MQ;
    int g = blockIdx.x * GPB + threadIdx.x / MQ;
    int j = threadIdx.x % MQ;
    if (g >= n) return;

    float4 acc = hnv[(size_t)g * MQ + j];  // self-loop
    int e = rowptr[g];
    const int end = rowptr[g + 1];
    for (; e + 1 < end; e += 2) {
        int s0 = csr_src[e];
        int s1 = csr_src[e + 1];
        float4 a = hnv[(size_t)s0 * MQ + j];
        float4 b = hnv[(size_t)s1 * MQ + j];
        acc.x += a.x + b.x;
        acc.y += a.y + b.y;
        acc.z += a.z + b.z;
        acc.w += a.w + b.w;
    }
    if (e < end) {
        int s0 = csr_src[e];
        float4 a = hnv[(size_t)s0 * MQ + j];
        acc.x += a.x; acc.y += a.y; acc.z += a.z; acc.w += a.w;
    }

    float s = dinv[g];
    float4 bv = biasv[j];
    float4 r;
    r.x = s * acc.x + bv.x;
    r.y = s * acc.y + bv.y;
    r.z = s * acc.z + bv.z;
    r.w = s * acc.w + bv.w;
    if (RELU) {
        r.x = fmaxf(r.x, 0.0f); r.y = fmaxf(r.y, 0.0f);
        r.z = fmaxf(r.z, 0.0f); r.w = fmaxf(r.w, 0.0f);
    }
    outv[(size_t)g * MQ + j] = r;
}

extern "C" void kernel_launch(void* const* d_in, const int* in_sizes, int n_in,
                              void* d_out, int out_size, void* d_ws, size_t ws_size,
                              hipStream_t stream) {
    const float* x  = (const float*)d_in[0];
    const int*   ei = (const int*)d_in[1];
    const float* W1 = (const float*)d_in[2];
    const float* b1 = (const float*)d_in[3];
    const float* W2 = (const float*)d_in[4];
    const float* b2 = (const float*)d_in[5];

    const int N = N_NODES;
    const int E = in_sizes[1] / 2;
    const int* src = ei;
    const int* dst = ei + E;

    char* ws = (char*)d_ws;
    size_t off = 0;
    auto carve = [&](size_t bytes) {
        char* p = ws + off;
        off += (bytes + 255) & ~(size_t)255;
        return p;
    };
    int*   hist    = (int*)  carve((size_t)N * 4);
    int*   excl    = (int*)  carve((size_t)N * 4);
    int*   bsums   = (int*)  carve(256 * 4);
    int*   rowptr  = (int*)  carve((size_t)(N + 1) * 4);
    int*   cursor  = (int*)  carve((size_t)N * 4);
    int*   csr_src = (int*)  carve((size_t)E * 4);
    float* dinv    = (float*)carve((size_t)N * 4);
    unsigned short* W1th = (unsigned short*)carve((size_t)256 * 128 * 2);
    unsigned short* W1tl = (unsigned short*)carve((size_t)256 * 128 * 2);
    unsigned short* W2th = (unsigned short*)carve((size_t)128 * 64 * 2);
    unsigned short* W2tl = (unsigned short*)carve((size_t)128 * 64 * 2);
    float* hn1     = (float*)carve((size_t)N * 128 * 4);
    float* h1      = (float*)carve((size_t)N * 128 * 4);
    float* hn2     = hn1;  // hn1 dead after gather1 writes h1

    const int NB = (N + 255) / 256;

    // ---- CSR build + dinv ----
    hipMemsetAsync(hist, 0, (size_t)N * 4, stream);
    hist_count<<<(E + 255) / 256, 256, 0, stream>>>(dst, hist, E);
    scan1<<<NB, 256, 0, stream>>>(hist, excl, bsums, N);
    scan2<<<1, 256, 0, stream>>>(bsums, NB);
    scan3<<<NB, 256, 0, stream>>>(excl, bsums, hist, rowptr, cursor, dinv, N, E);
    csr_fill<<<(E + 255) / 256, 256, 0, stream>>>(src, dst, cursor, csr_src, E);

    // ---- weight transpose + split (tiny) ----
    wsplit<<<(256 * 128 + 255) / 256, 256, 0, stream>>>(W1, W1th, W1tl, 256, 7);
    wsplit<<<(128 * 64 + 255) / 256, 256, 0, stream>>>(W2, W2th, W2tl, 128, 6);

    const int GB = (N + 63) / 64;  // 782 blocks

    // ---- layer 1 ----
    gemm_mfma_split<256, 128><<<GB, 256, 0, stream>>>(x, W1th, W1tl, dinv, hn1, N);
    {
        const int GPB = 256 / 32;
        gather_agg<true, 32><<<(N + GPB - 1) / GPB, 256, 0, stream>>>(
            (const float4*)hn1, rowptr, csr_src, dinv, (const float4*)b1,
            (float4*)h1, N);
    }

    // ---- layer 2 ----
    gemm_mfma_split<128, 64><<<GB, 256, 0, stream>>>(h1, W2th, W2tl, dinv, hn2, N);
    {
        const int GPB = 256 / 16;
        gather_agg<false, 16><<<(N + GPB - 1) / GPB, 256, 0, stream>>>(
            (const float4*)hn2, rowptr, csr_src, dinv, (const float4*)b2,
            (float4*)d_out, N);
    }
}

// Round 4
// 310.547 us; speedup vs baseline: 7.3766x; 1.1596x over previous
//
#include <hip/hip_runtime.h>

#define N_NODES 50000

typedef short bf16x8 __attribute__((ext_vector_type(8)));
typedef float f32x4 __attribute__((ext_vector_type(4)));

__device__ inline unsigned short f2bf(float f) {
    union { float f; unsigned u; } v; v.f = f;
    unsigned u = v.u;
    unsigned lsb = (u >> 16) & 1u;
    u += 0x7fffu + lsb;  // round-to-nearest-even
    return (unsigned short)(u >> 16);
}

__device__ inline float bf2f(unsigned short h) {
    union { unsigned u; float f; } v; v.u = ((unsigned)h) << 16;
    return v.f;
}

// ============ CSR build: histogram -> scan -> fill ============

__global__ __launch_bounds__(256) void hist_count(const int* __restrict__ dst,
                                                  int* __restrict__ hist, int E) {
    int i = blockIdx.x * 256 + threadIdx.x;
    if (i < E) atomicAdd(&hist[dst[i]], 1);
}

__global__ __launch_bounds__(256) void scan1(const int* __restrict__ hist,
                                             int* __restrict__ excl,
                                             int* __restrict__ blocksums, int n) {
    __shared__ int sh[256];
    int i = blockIdx.x * 256 + threadIdx.x;
    int v = (i < n) ? hist[i] : 0;
    sh[threadIdx.x] = v;
    __syncthreads();
    for (int off = 1; off < 256; off <<= 1) {
        int t = (threadIdx.x >= off) ? sh[threadIdx.x - off] : 0;
        __syncthreads();
        sh[threadIdx.x] += t;
        __syncthreads();
    }
    if (i < n) excl[i] = sh[threadIdx.x] - v;
    if (threadIdx.x == 255) blocksums[blockIdx.x] = sh[255];
}

__global__ __launch_bounds__(256) void scan2(int* __restrict__ blocksums, int nb) {
    __shared__ int sh[256];
    int v = (threadIdx.x < nb) ? blocksums[threadIdx.x] : 0;
    sh[threadIdx.x] = v;
    __syncthreads();
    for (int off = 1; off < 256; off <<= 1) {
        int t = (threadIdx.x >= off) ? sh[threadIdx.x - off] : 0;
        __syncthreads();
        sh[threadIdx.x] += t;
        __syncthreads();
    }
    if (threadIdx.x < nb) blocksums[threadIdx.x] = sh[threadIdx.x] - v;
}

__global__ __launch_bounds__(256) void scan3(const int* __restrict__ excl,
                                             const int* __restrict__ blocksums,
                                             const int* __restrict__ hist,
                                             int* __restrict__ rowptr,
                                             int* __restrict__ cursor,
                                             float* __restrict__ dinv,
                                             int n, int E) {
    int i = blockIdx.x * 256 + threadIdx.x;
    if (i < n) {
        int r = excl[i] + blocksums[blockIdx.x];
        rowptr[i] = r;
        cursor[i] = r;
        dinv[i] = rsqrtf((float)(hist[i] + 1));  // +1 self-loop
    }
    if (i == 0) rowptr[n] = E;
}

__global__ __launch_bounds__(256) void csr_fill(const int* __restrict__ src,
                                                const int* __restrict__ dst,
                                                int* __restrict__ cursor,
                                                int* __restrict__ csr_src, int E) {
    int e = blockIdx.x * 256 + threadIdx.x;
    if (e < E) {
        int pos = atomicAdd(&cursor[dst[e]], 1);
        csr_src[pos] = src[e];
    }
}

// ============ W transpose + hi/lo bf16 split ============
__global__ __launch_bounds__(256) void wsplit(const float* __restrict__ W,
                                              unsigned short* __restrict__ Th,
                                              unsigned short* __restrict__ Tl,
                                              int K, int logM) {
    int i = blockIdx.x * 256 + threadIdx.x;
    int M = 1 << logM;
    if (i >= K * M) return;
    int k = i >> logM;
    int n = i & (M - 1);
    float v = W[i];
    unsigned short h = f2bf(v);
    float r = v - bf2f(h);
    Th[(size_t)n * K + k] = h;
    Tl[(size_t)n * K + k] = f2bf(r);
}

// ============ MFMA GEMM v2: LDS-staged A (bf16 hi/lo), B in registers ============
// C[r,c] = dinv[r] * sum_k A[r,k]*B[k,c]; Bt pre-split/transposed [M][K].
// Block: 64 rows x M cols; M/16 waves, wave w owns col-tile w (all 64 rows).
// A tile (64 x 32 fp32) staged cooperatively each K-step: coalesced float4
// loads (prefetched 1 step ahead), split to bf16 hi/lo once, stored to padded
// LDS (stride 40 ushort = 80 B: 2-way bank conflict only), read as b128 frags.
template <int K, int M>
__global__ __launch_bounds__(M * 4) void gemm_mfma_v2(const float* __restrict__ A,
                                                      const unsigned short* __restrict__ Bth,
                                                      const unsigned short* __restrict__ Btl,
                                                      const float* __restrict__ dinv,
                                                      float* __restrict__ C, int N) {
    const int KS = K / 32;        // K-steps
    const int THREADS = M * 4;    // M/16 waves * 64
    const int CPT = 512 / THREADS;  // float4 chunks per thread (A tile = 512 x 16B)

    __shared__ __align__(16) unsigned short Ah[64 * 40];
    __shared__ __align__(16) unsigned short Al[64 * 40];

    const int tid = threadIdx.x;
    const int wave = tid >> 6;    // = col tile
    const int lane = tid & 63;
    const int n16 = lane & 15;
    const int quad = lane >> 4;
    const int row0 = blockIdx.x * 64;

    // ---- preload B fragments (hi/lo) for all K-steps into registers ----
    bf16x8 bh[KS], bl[KS];
    {
        const size_t brow = (size_t)(wave * 16 + n16) * K + quad * 8;
#pragma unroll
        for (int ks = 0; ks < KS; ks++) {
            bh[ks] = *(const bf16x8*)(Bth + brow + ks * 32);
            bl[ks] = *(const bf16x8*)(Btl + brow + ks * 32);
        }
    }

    // ---- A staging addresses (chunk q covers row r=q>>3, 16B-unit c4=q&7) ----
    int ar[CPT];
    int ac4[CPT];
#pragma unroll
    for (int p = 0; p < CPT; p++) {
        int q = p * THREADS + tid;
        int r = q >> 3;
        ac4[p] = q & 7;
        int grow = row0 + r;
        ar[p] = r;
        if (grow >= N) grow = N - 1;  // clamp (garbage rows never stored)
        // stash global row base in r? keep separate pointer below
        ar[p] = (grow << 3) | (q & 7);  // pack: grow*8 + c4 -> chunk addr in 16B units of row-major A? no:
    }
    // simpler: recompute inline below

    f32x4 acc[4] = {};

    float4 pre[CPT];
    // prefetch tile 0
#pragma unroll
    for (int p = 0; p < CPT; p++) {
        int q = p * THREADS + tid;
        int grow = row0 + (q >> 3);
        if (grow >= N) grow = N - 1;
        pre[p] = *(const float4*)(A + (size_t)grow * K + (q & 7) * 4);
    }

#pragma unroll
    for (int ks = 0; ks < KS; ks++) {
        if (ks) __syncthreads();  // prev compute done; LDS reusable
        // convert + store staged tile
#pragma unroll
        for (int p = 0; p < CPT; p++) {
            int q = p * THREADS + tid;
            int r = q >> 3;
            int c4 = q & 7;
            float av[4] = {pre[p].x, pre[p].y, pre[p].z, pre[p].w};
            ushort4 h4, l4;
            unsigned short* hp = (unsigned short*)&h4;
            unsigned short* lp = (unsigned short*)&l4;
#pragma unroll
            for (int j = 0; j < 4; j++) {
                unsigned short h = f2bf(av[j]);
                hp[j] = h;
                lp[j] = f2bf(av[j] - bf2f(h));
            }
            *(ushort4*)(Ah + r * 40 + c4 * 4) = h4;
            *(ushort4*)(Al + r * 40 + c4 * 4) = l4;
        }
        // issue prefetch for next tile before the barrier (overlaps compute)
        if (ks + 1 < KS) {
#pragma unroll
            for (int p = 0; p < CPT; p++) {
                int q = p * THREADS + tid;
                int grow = row0 + (q >> 3);
                if (grow >= N) grow = N - 1;
                pre[p] = *(const float4*)(A + (size_t)grow * K + (ks + 1) * 32 + (q & 7) * 4);
            }
        }
        __syncthreads();
        // compute: 4 row-tiles x this wave's col-tile
#pragma unroll
        for (int rt = 0; rt < 4; rt++) {
            const int ro = (rt * 16 + n16) * 40 + quad * 8;
            bf16x8 ah = *(const bf16x8*)(Ah + ro);
            bf16x8 al = *(const bf16x8*)(Al + ro);
            acc[rt] = __builtin_amdgcn_mfma_f32_16x16x32_bf16(ah, bh[ks], acc[rt], 0, 0, 0);
            acc[rt] = __builtin_amdgcn_mfma_f32_16x16x32_bf16(ah, bl[ks], acc[rt], 0, 0, 0);
            acc[rt] = __builtin_amdgcn_mfma_f32_16x16x32_bf16(al, bh[ks], acc[rt], 0, 0, 0);
        }
    }

    // ---- epilogue: D mapping col = lane&15, row = quad*4 + reg ----
#pragma unroll
    for (int rt = 0; rt < 4; rt++) {
        const int orow_base = row0 + rt * 16 + quad * 4;
#pragma unroll
        for (int r = 0; r < 4; r++) {
            int orow = orow_base + r;
            if (orow < N) {
                C[(size_t)orow * M + wave * 16 + n16] = dinv[orow] * acc[rt][r];
            }
        }
    }
}

// ============ fused gather-aggregate + epilogue ============
template <bool RELU, int MQ>
__global__ __launch_bounds__(256) void gather_agg(const float4* __restrict__ hnv,
                                                  const int* __restrict__ rowptr,
                                                  const int* __restrict__ csr_src,
                                                  const float* __restrict__ dinv,
                                                  const float4* __restrict__ biasv,
                                                  float4* __restrict__ outv, int n) {
    const int GPB = 256 / MQ;
    int g = blockIdx.x * GPB + threadIdx.x / MQ;
    int j = threadIdx.x % MQ;
    if (g >= n) return;

    float4 acc = hnv[(size_t)g * MQ + j];  // self-loop
    int e = rowptr[g];
    const int end = rowptr[g + 1];
    for (; e + 3 < end; e += 4) {
        int s0 = csr_src[e];
        int s1 = csr_src[e + 1];
        int s2 = csr_src[e + 2];
        int s3 = csr_src[e + 3];
        float4 a = hnv[(size_t)s0 * MQ + j];
        float4 b = hnv[(size_t)s1 * MQ + j];
        float4 c = hnv[(size_t)s2 * MQ + j];
        float4 d = hnv[(size_t)s3 * MQ + j];
        acc.x += (a.x + b.x) + (c.x + d.x);
        acc.y += (a.y + b.y) + (c.y + d.y);
        acc.z += (a.z + b.z) + (c.z + d.z);
        acc.w += (a.w + b.w) + (c.w + d.w);
    }
    for (; e < end; e++) {
        int s0 = csr_src[e];
        float4 a = hnv[(size_t)s0 * MQ + j];
        acc.x += a.x; acc.y += a.y; acc.z += a.z; acc.w += a.w;
    }

    float s = dinv[g];
    float4 bv = biasv[j];
    float4 r;
    r.x = s * acc.x + bv.x;
    r.y = s * acc.y + bv.y;
    r.z = s * acc.z + bv.z;
    r.w = s * acc.w + bv.w;
    if (RELU) {
        r.x = fmaxf(r.x, 0.0f); r.y = fmaxf(r.y, 0.0f);
        r.z = fmaxf(r.z, 0.0f); r.w = fmaxf(r.w, 0.0f);
    }
    outv[(size_t)g * MQ + j] = r;
}

extern "C" void kernel_launch(void* const* d_in, const int* in_sizes, int n_in,
                              void* d_out, int out_size, void* d_ws, size_t ws_size,
                              hipStream_t stream) {
    const float* x  = (const float*)d_in[0];
    const int*   ei = (const int*)d_in[1];
    const float* W1 = (const float*)d_in[2];
    const float* b1 = (const float*)d_in[3];
    const float* W2 = (const float*)d_in[4];
    const float* b2 = (const float*)d_in[5];

    const int N = N_NODES;
    const int E = in_sizes[1] / 2;
    const int* src = ei;
    const int* dst = ei + E;

    char* ws = (char*)d_ws;
    size_t off = 0;
    auto carve = [&](size_t bytes) {
        char* p = ws + off;
        off += (bytes + 255) & ~(size_t)255;
        return p;
    };
    int*   hist    = (int*)  carve((size_t)N * 4);
    int*   excl    = (int*)  carve((size_t)N * 4);
    int*   bsums   = (int*)  carve(256 * 4);
    int*   rowptr  = (int*)  carve((size_t)(N + 1) * 4);
    int*   cursor  = (int*)  carve((size_t)N * 4);
    int*   csr_src = (int*)  carve((size_t)E * 4);
    float* dinv    = (float*)carve((size_t)N * 4);
    unsigned short* W1th = (unsigned short*)carve((size_t)256 * 128 * 2);
    unsigned short* W1tl = (unsigned short*)carve((size_t)256 * 128 * 2);
    unsigned short* W2th = (unsigned short*)carve((size_t)128 * 64 * 2);
    unsigned short* W2tl = (unsigned short*)carve((size_t)128 * 64 * 2);
    float* hn1     = (float*)carve((size_t)N * 128 * 4);
    float* h1      = (float*)carve((size_t)N * 128 * 4);
    float* hn2     = hn1;  // hn1 dead after gather1 writes h1

    const int NB = (N + 255) / 256;

    // ---- CSR build + dinv ----
    hipMemsetAsync(hist, 0, (size_t)N * 4, stream);
    hist_count<<<(E + 255) / 256, 256, 0, stream>>>(dst, hist, E);
    scan1<<<NB, 256, 0, stream>>>(hist, excl, bsums, N);
    scan2<<<1, 256, 0, stream>>>(bsums, NB);
    scan3<<<NB, 256, 0, stream>>>(excl, bsums, hist, rowptr, cursor, dinv, N, E);
    csr_fill<<<(E + 255) / 256, 256, 0, stream>>>(src, dst, cursor, csr_src, E);

    // ---- weight transpose + split (tiny) ----
    wsplit<<<(256 * 128 + 255) / 256, 256, 0, stream>>>(W1, W1th, W1tl, 256, 7);
    wsplit<<<(128 * 64 + 255) / 256, 256, 0, stream>>>(W2, W2th, W2tl, 128, 6);

    const int GB = (N + 63) / 64;  // 782 blocks

    // ---- layer 1 ----
    gemm_mfma_v2<256, 128><<<GB, 512, 0, stream>>>(x, W1th, W1tl, dinv, hn1, N);
    {
        const int GPB = 256 / 32;
        gather_agg<true, 32><<<(N + GPB - 1) / GPB, 256, 0, stream>>>(
            (const float4*)hn1, rowptr, csr_src, dinv, (const float4*)b1,
            (float4*)h1, N);
    }

    // ---- layer 2 ----
    gemm_mfma_v2<128, 64><<<GB, 256, 0, stream>>>(h1, W2th, W2tl, dinv, hn2, N);
    {
        const int GPB = 256 / 16;
        gather_agg<false, 16><<<(N + GPB - 1) / GPB, 256, 0, stream>>>(
            (const float4*)hn2, rowptr, csr_src, dinv, (const float4*)b2,
            (float4*)d_out, N);
    }
}

// Round 5
// 275.551 us; speedup vs baseline: 8.3134x; 1.1270x over previous
//
#include <hip/hip_runtime.h>

#define N_NODES 50000

typedef short bf16x8 __attribute__((ext_vector_type(8)));
typedef float f32x4 __attribute__((ext_vector_type(4)));

__device__ inline unsigned short f2bf(float f) {
    union { float f; unsigned u; } v; v.f = f;
    unsigned u = v.u;
    unsigned lsb = (u >> 16) & 1u;
    u += 0x7fffu + lsb;  // round-to-nearest-even
    return (unsigned short)(u >> 16);
}

__device__ inline float bf2f(unsigned short h) {
    union { unsigned u; float f; } v; v.u = ((unsigned)h) << 16;
    return v.f;
}

// ============ CSR build: histogram -> scan -> fill ============

__global__ __launch_bounds__(256) void hist_count(const int* __restrict__ dst,
                                                  int* __restrict__ hist, int E) {
    int i = blockIdx.x * 256 + threadIdx.x;
    if (i < E) atomicAdd(&hist[dst[i]], 1);
}

__global__ __launch_bounds__(256) void scan1(const int* __restrict__ hist,
                                             int* __restrict__ excl,
                                             int* __restrict__ blocksums, int n) {
    __shared__ int sh[256];
    int i = blockIdx.x * 256 + threadIdx.x;
    int v = (i < n) ? hist[i] : 0;
    sh[threadIdx.x] = v;
    __syncthreads();
    for (int off = 1; off < 256; off <<= 1) {
        int t = (threadIdx.x >= off) ? sh[threadIdx.x - off] : 0;
        __syncthreads();
        sh[threadIdx.x] += t;
        __syncthreads();
    }
    if (i < n) excl[i] = sh[threadIdx.x] - v;
    if (threadIdx.x == 255) blocksums[blockIdx.x] = sh[255];
}

__global__ __launch_bounds__(256) void scan2(int* __restrict__ blocksums, int nb) {
    __shared__ int sh[256];
    int v = (threadIdx.x < nb) ? blocksums[threadIdx.x] : 0;
    sh[threadIdx.x] = v;
    __syncthreads();
    for (int off = 1; off < 256; off <<= 1) {
        int t = (threadIdx.x >= off) ? sh[threadIdx.x - off] : 0;
        __syncthreads();
        sh[threadIdx.x] += t;
        __syncthreads();
    }
    if (threadIdx.x < nb) blocksums[threadIdx.x] = sh[threadIdx.x] - v;
}

__global__ __launch_bounds__(256) void scan3(const int* __restrict__ excl,
                                             const int* __restrict__ blocksums,
                                             const int* __restrict__ hist,
                                             int* __restrict__ rowptr,
                                             int* __restrict__ cursor,
                                             float* __restrict__ dinv,
                                             int n, int E) {
    int i = blockIdx.x * 256 + threadIdx.x;
    if (i < n) {
        int r = excl[i] + blocksums[blockIdx.x];
        rowptr[i] = r;
        cursor[i] = r;
        dinv[i] = rsqrtf((float)(hist[i] + 1));  // +1 self-loop
    }
    if (i == 0) rowptr[n] = E;
}

__global__ __launch_bounds__(256) void csr_fill(const int* __restrict__ src,
                                                const int* __restrict__ dst,
                                                int* __restrict__ cursor,
                                                int* __restrict__ csr_src, int E) {
    int e = blockIdx.x * 256 + threadIdx.x;
    if (e < E) {
        int pos = atomicAdd(&cursor[dst[e]], 1);
        csr_src[pos] = src[e];
    }
}

// ============ W transpose + hi/lo bf16 split ============
__global__ __launch_bounds__(256) void wsplit(const float* __restrict__ W,
                                              unsigned short* __restrict__ Th,
                                              unsigned short* __restrict__ Tl,
                                              int K, int logM) {
    int i = blockIdx.x * 256 + threadIdx.x;
    int M = 1 << logM;
    if (i >= K * M) return;
    int k = i >> logM;
    int n = i & (M - 1);
    float v = W[i];
    unsigned short h = f2bf(v);
    float r = v - bf2f(h);
    Th[(size_t)n * K + k] = h;
    Tl[(size_t)n * K + k] = f2bf(r);
}

// ============ MFMA GEMM v3: dbuf LDS-staged A (bf16 hi/lo), B in regs,
//              bf16 output ============
// Cb[r,c] = bf16( dinv[r] * sum_k A[r,k]*B[k,c] ); Bt pre-split [M][K].
// Block: 64 rows x M cols; M/16 waves. One barrier per K-step (double buffer).
template <int K, int M>
__global__ __launch_bounds__(M * 4) void gemm_mfma_v3(const float* __restrict__ A,
                                                      const unsigned short* __restrict__ Bth,
                                                      const unsigned short* __restrict__ Btl,
                                                      const float* __restrict__ dinv,
                                                      unsigned short* __restrict__ Cb, int N) {
    const int KS = K / 32;
    const int THREADS = M * 4;
    const int CPT = 512 / THREADS;  // float4 chunks per thread (tile = 512 chunks)
    const int PL = 64 * 40;         // plane size (ushorts) per buffer

    __shared__ __align__(16) unsigned short Ah[2 * PL];
    __shared__ __align__(16) unsigned short Al[2 * PL];

    const int tid = threadIdx.x;
    const int wave = tid >> 6;  // col tile
    const int lane = tid & 63;
    const int n16 = lane & 15;
    const int quad = lane >> 4;
    const int row0 = blockIdx.x * 64;

    // B fragments (all K-steps) in registers
    bf16x8 bh[KS], bl[KS];
    {
        const size_t brow = (size_t)(wave * 16 + n16) * K + quad * 8;
#pragma unroll
        for (int ks = 0; ks < KS; ks++) {
            bh[ks] = *(const bf16x8*)(Bth + brow + ks * 32);
            bl[ks] = *(const bf16x8*)(Btl + brow + ks * 32);
        }
    }

    // staging lambdas
    int srow[CPT], sc4[CPT];
    const float* aptr[CPT];
#pragma unroll
    for (int p = 0; p < CPT; p++) {
        int q = p * THREADS + tid;
        srow[p] = q >> 3;
        sc4[p] = q & 7;
        int grow = row0 + srow[p];
        if (grow >= N) grow = N - 1;
        aptr[p] = A + (size_t)grow * K + sc4[p] * 4;
    }

    float4 pre[CPT];
#pragma unroll
    for (int p = 0; p < CPT; p++) pre[p] = *(const float4*)(aptr[p]);  // ks=0

    // store tile 0 into buf 0
#pragma unroll
    for (int p = 0; p < CPT; p++) {
        ushort4 h4, l4;
        unsigned short* hp = (unsigned short*)&h4;
        unsigned short* lp = (unsigned short*)&l4;
        float av[4] = {pre[p].x, pre[p].y, pre[p].z, pre[p].w};
#pragma unroll
        for (int j = 0; j < 4; j++) {
            unsigned short h = f2bf(av[j]);
            hp[j] = h;
            lp[j] = f2bf(av[j] - bf2f(h));
        }
        *(ushort4*)(Ah + srow[p] * 40 + sc4[p] * 4) = h4;
        *(ushort4*)(Al + srow[p] * 40 + sc4[p] * 4) = l4;
    }
    if (KS > 1) {
#pragma unroll
        for (int p = 0; p < CPT; p++) pre[p] = *(const float4*)(aptr[p] + 32);  // ks=1
    }
    __syncthreads();

    f32x4 acc[4] = {};

#pragma unroll
    for (int ks = 0; ks < KS; ks++) {
        const int cur = (ks & 1) * PL;
        // compute from current buffer
#pragma unroll
        for (int rt = 0; rt < 4; rt++) {
            const int ro = cur + (rt * 16 + n16) * 40 + quad * 8;
            bf16x8 ah = *(const bf16x8*)(Ah + ro);
            bf16x8 al = *(const bf16x8*)(Al + ro);
            acc[rt] = __builtin_amdgcn_mfma_f32_16x16x32_bf16(ah, bh[ks], acc[rt], 0, 0, 0);
            acc[rt] = __builtin_amdgcn_mfma_f32_16x16x32_bf16(ah, bl[ks], acc[rt], 0, 0, 0);
            acc[rt] = __builtin_amdgcn_mfma_f32_16x16x32_bf16(al, bh[ks], acc[rt], 0, 0, 0);
        }
        // stage next tile into other buffer; prefetch tile after
        if (ks + 1 < KS) {
            const int nxt = ((ks + 1) & 1) * PL;
#pragma unroll
            for (int p = 0; p < CPT; p++) {
                ushort4 h4, l4;
                unsigned short* hp = (unsigned short*)&h4;
                unsigned short* lp = (unsigned short*)&l4;
                float av[4] = {pre[p].x, pre[p].y, pre[p].z, pre[p].w};
#pragma unroll
                for (int j = 0; j < 4; j++) {
                    unsigned short h = f2bf(av[j]);
                    hp[j] = h;
                    lp[j] = f2bf(av[j] - bf2f(h));
                }
                *(ushort4*)(Ah + nxt + srow[p] * 40 + sc4[p] * 4) = h4;
                *(ushort4*)(Al + nxt + srow[p] * 40 + sc4[p] * 4) = l4;
            }
            if (ks + 2 < KS) {
#pragma unroll
                for (int p = 0; p < CPT; p++)
                    pre[p] = *(const float4*)(aptr[p] + (ks + 2) * 32);
            }
        }
        __syncthreads();
    }

    // epilogue: D mapping col = lane&15, row = quad*4 + reg; bf16 store
#pragma unroll
    for (int rt = 0; rt < 4; rt++) {
        const int orow_base = row0 + rt * 16 + quad * 4;
#pragma unroll
        for (int r = 0; r < 4; r++) {
            int orow = orow_base + r;
            if (orow < N) {
                Cb[(size_t)orow * M + wave * 16 + n16] = f2bf(dinv[orow] * acc[rt][r]);
            }
        }
    }
}

// ============ fused gather-aggregate (bf16 rows) + epilogue (fp32 out) ============
// out[v,:] = [relu]( dinv[v] * (sum_{e in in(v)} hnb[src_e,:] + hnb[v,:]) + bias )
template <bool RELU, int M>
__global__ __launch_bounds__(256) void gather_agg_bf(const unsigned short* __restrict__ hnb,
                                                     const int* __restrict__ rowptr,
                                                     const int* __restrict__ csr_src,
                                                     const float* __restrict__ dinv,
                                                     const float* __restrict__ bias,
                                                     float* __restrict__ outp, int n) {
    const int MQ = M / 8;        // ushort8 chunks per row
    const int GPB = 256 / MQ;
    int g = blockIdx.x * GPB + threadIdx.x / MQ;
    int j = threadIdx.x % MQ;
    if (g >= n) return;

    float acc[8] = {};
    {
        bf16x8 v = *(const bf16x8*)(hnb + (size_t)g * M + j * 8);  // self-loop
#pragma unroll
        for (int i = 0; i < 8; i++) acc[i] = bf2f((unsigned short)v[i]);
    }

    int e = rowptr[g];
    const int end = rowptr[g + 1];
    for (; e + 3 < end; e += 4) {
        int s0 = csr_src[e];
        int s1 = csr_src[e + 1];
        int s2 = csr_src[e + 2];
        int s3 = csr_src[e + 3];
        bf16x8 v0 = *(const bf16x8*)(hnb + (size_t)s0 * M + j * 8);
        bf16x8 v1 = *(const bf16x8*)(hnb + (size_t)s1 * M + j * 8);
        bf16x8 v2 = *(const bf16x8*)(hnb + (size_t)s2 * M + j * 8);
        bf16x8 v3 = *(const bf16x8*)(hnb + (size_t)s3 * M + j * 8);
#pragma unroll
        for (int i = 0; i < 8; i++) {
            acc[i] += (bf2f((unsigned short)v0[i]) + bf2f((unsigned short)v1[i])) +
                      (bf2f((unsigned short)v2[i]) + bf2f((unsigned short)v3[i]));
        }
    }
    for (; e < end; e++) {
        int s0 = csr_src[e];
        bf16x8 v0 = *(const bf16x8*)(hnb + (size_t)s0 * M + j * 8);
#pragma unroll
        for (int i = 0; i < 8; i++) acc[i] += bf2f((unsigned short)v0[i]);
    }

    const float s = dinv[g];
    float r[8];
#pragma unroll
    for (int i = 0; i < 8; i++) {
        r[i] = s * acc[i] + bias[j * 8 + i];
        if (RELU) r[i] = fmaxf(r[i], 0.0f);
    }
    float* op = outp + (size_t)g * M + j * 8;
    *(float4*)(op) = make_float4(r[0], r[1], r[2], r[3]);
    *(float4*)(op + 4) = make_float4(r[4], r[5], r[6], r[7]);
}

extern "C" void kernel_launch(void* const* d_in, const int* in_sizes, int n_in,
                              void* d_out, int out_size, void* d_ws, size_t ws_size,
                              hipStream_t stream) {
    const float* x  = (const float*)d_in[0];
    const int*   ei = (const int*)d_in[1];
    const float* W1 = (const float*)d_in[2];
    const float* b1 = (const float*)d_in[3];
    const float* W2 = (const float*)d_in[4];
    const float* b2 = (const float*)d_in[5];

    const int N = N_NODES;
    const int E = in_sizes[1] / 2;
    const int* src = ei;
    const int* dst = ei + E;

    char* ws = (char*)d_ws;
    size_t off = 0;
    auto carve = [&](size_t bytes) {
        char* p = ws + off;
        off += (bytes + 255) & ~(size_t)255;
        return p;
    };
    int*   hist    = (int*)  carve((size_t)N * 4);
    int*   excl    = (int*)  carve((size_t)N * 4);
    int*   bsums   = (int*)  carve(256 * 4);
    int*   rowptr  = (int*)  carve((size_t)(N + 1) * 4);
    int*   cursor  = (int*)  carve((size_t)N * 4);
    int*   csr_src = (int*)  carve((size_t)E * 4);
    float* dinv    = (float*)carve((size_t)N * 4);
    unsigned short* W1th = (unsigned short*)carve((size_t)256 * 128 * 2);
    unsigned short* W1tl = (unsigned short*)carve((size_t)256 * 128 * 2);
    unsigned short* W2th = (unsigned short*)carve((size_t)128 * 64 * 2);
    unsigned short* W2tl = (unsigned short*)carve((size_t)128 * 64 * 2);
    unsigned short* hn1b = (unsigned short*)carve((size_t)N * 128 * 2);  // bf16
    float*          h1   = (float*)carve((size_t)N * 128 * 4);           // fp32
    unsigned short* hn2b = hn1b;  // hn1b dead after gather1

    const int NB = (N + 255) / 256;

    // ---- CSR build + dinv ----
    hipMemsetAsync(hist, 0, (size_t)N * 4, stream);
    hist_count<<<(E + 255) / 256, 256, 0, stream>>>(dst, hist, E);
    scan1<<<NB, 256, 0, stream>>>(hist, excl, bsums, N);
    scan2<<<1, 256, 0, stream>>>(bsums, NB);
    scan3<<<NB, 256, 0, stream>>>(excl, bsums, hist, rowptr, cursor, dinv, N, E);
    csr_fill<<<(E + 255) / 256, 256, 0, stream>>>(src, dst, cursor, csr_src, E);

    // ---- weight transpose + split (tiny) ----
    wsplit<<<(256 * 128 + 255) / 256, 256, 0, stream>>>(W1, W1th, W1tl, 256, 7);
    wsplit<<<(128 * 64 + 255) / 256, 256, 0, stream>>>(W2, W2th, W2tl, 128, 6);

    const int GB = (N + 63) / 64;  // 782 blocks

    // ---- layer 1 ----
    gemm_mfma_v3<256, 128><<<GB, 512, 0, stream>>>(x, W1th, W1tl, dinv, hn1b, N);
    {
        const int GPB = 256 / (128 / 8);  // 16 nodes/block
        gather_agg_bf<true, 128><<<(N + GPB - 1) / GPB, 256, 0, stream>>>(
            hn1b, rowptr, csr_src, dinv, b1, h1, N);
    }

    // ---- layer 2 ----
    gemm_mfma_v3<128, 64><<<GB, 256, 0, stream>>>(h1, W2th, W2tl, dinv, hn2b, N);
    {
        const int GPB = 256 / (64 / 8);  // 32 nodes/block
        gather_agg_bf<false, 64><<<(N + GPB - 1) / GPB, 256, 0, stream>>>(
            hn2b, rowptr, csr_src, dinv, b2, (float*)d_out, N);
    }
}

// Round 6
// 212.323 us; speedup vs baseline: 10.7891x; 1.2978x over previous
//
#include <hip/hip_runtime.h>

#define N_NODES 50000
#define NCH 256          // edge chunks (blocks in B1/B2)
#define NBKT 256         // bucket slots (dst>>8; 196 live for N=50000)

typedef short bf16x8 __attribute__((ext_vector_type(8)));
typedef float f32x4 __attribute__((ext_vector_type(4)));

__device__ inline unsigned short f2bf(float f) {
    union { float f; unsigned u; } v; v.f = f;
    unsigned u = v.u;
    unsigned lsb = (u >> 16) & 1u;
    u += 0x7fffu + lsb;  // round-to-nearest-even
    return (unsigned short)(u >> 16);
}

__device__ inline float bf2f(unsigned short h) {
    union { unsigned u; float f; } v; v.u = ((unsigned)h) << 16;
    return v.f;
}

// ============ bucketed counting-sort CSR build (no global atomics) ============

// B1: per-chunk bucket histogram -> cnt[c][b]
__global__ __launch_bounds__(256) void bkt_count(const int* __restrict__ dst,
                                                 int* __restrict__ cnt, int E, int epc) {
    __shared__ int h[NBKT];
    h[threadIdx.x] = 0;
    __syncthreads();
    const int c = blockIdx.x;
    const int e0 = c * epc;
    const int e1 = min(E, e0 + epc);
    for (int e = e0 + threadIdx.x; e < e1; e += 256)
        atomicAdd(&h[dst[e] >> 8], 1);
    __syncthreads();
    cnt[c * NBKT + threadIdx.x] = h[threadIdx.x];
}

// S1: per-bucket exclusive scan over chunks; off[c][b], total[b]
__global__ __launch_bounds__(256) void bkt_scan_chunks(const int* __restrict__ cnt,
                                                       int* __restrict__ off,
                                                       int* __restrict__ total) {
    __shared__ int sh[256];
    const int b = blockIdx.x;
    const int t = threadIdx.x;
    int v = cnt[t * NBKT + b];
    sh[t] = v;
    __syncthreads();
    for (int o = 1; o < 256; o <<= 1) {
        int u = (t >= o) ? sh[t - o] : 0;
        __syncthreads();
        sh[t] += u;
        __syncthreads();
    }
    off[t * NBKT + b] = sh[t] - v;
    if (t == 255) total[b] = sh[255];
}

// S2: scan totals -> bbase[0..256]; rowptr[N]=E
__global__ __launch_bounds__(256) void bkt_scan_base(const int* __restrict__ total,
                                                     int* __restrict__ bbase,
                                                     int* __restrict__ rowptr,
                                                     int N, int E) {
    __shared__ int sh[256];
    const int t = threadIdx.x;
    int v = total[t];
    sh[t] = v;
    __syncthreads();
    for (int o = 1; o < 256; o <<= 1) {
        int u = (t >= o) ? sh[t - o] : 0;
        __syncthreads();
        sh[t] += u;
        __syncthreads();
    }
    bbase[t] = sh[t] - v;
    if (t == 255) bbase[256] = sh[255];
    if (t == 0) rowptr[N] = E;
}

// B2: scatter (src,dst) pairs into bucket-sorted order; LDS cursors only
__global__ __launch_bounds__(256) void bkt_scatter(const int* __restrict__ src,
                                                   const int* __restrict__ dst,
                                                   const int* __restrict__ off,
                                                   const int* __restrict__ bbase,
                                                   uint2* __restrict__ pairs,
                                                   int E, int epc) {
    __shared__ int cur[NBKT];
    const int c = blockIdx.x;
    cur[threadIdx.x] = bbase[threadIdx.x] + off[c * NBKT + threadIdx.x];
    __syncthreads();
    const int e0 = c * epc;
    const int e1 = min(E, e0 + epc);
    for (int e = e0 + threadIdx.x; e < e1; e += 256) {
        int s = src[e];
        int d = dst[e];
        int pos = atomicAdd(&cur[d >> 8], 1);
        pairs[pos] = make_uint2((unsigned)s, (unsigned)d);
    }
}

// B3: per-bucket local CSR: rowptr, dinv, csr_src (dense regional writes)
__global__ __launch_bounds__(256) void bkt_csr(const uint2* __restrict__ pairs,
                                               const int* __restrict__ bbase,
                                               int* __restrict__ rowptr,
                                               int* __restrict__ csr_src,
                                               float* __restrict__ dinv, int N) {
    __shared__ int lh[256];
    __shared__ int sc[256];
    __shared__ int lcur[256];
    const int b = blockIdx.x;
    const int t = threadIdx.x;
    const int ebase = bbase[b];
    const int eend = bbase[b + 1];
    const int node0 = b << 8;

    lh[t] = 0;
    __syncthreads();
    for (int e = ebase + t; e < eend; e += 256)
        atomicAdd(&lh[pairs[e].y & 255], 1);
    __syncthreads();
    int v = lh[t];
    sc[t] = v;
    __syncthreads();
    for (int o = 1; o < 256; o <<= 1) {
        int u = (t >= o) ? sc[t - o] : 0;
        __syncthreads();
        sc[t] += u;
        __syncthreads();
    }
    const int excl = sc[t] - v;
    lcur[t] = ebase + excl;
    const int node = node0 + t;
    if (node < N) {
        rowptr[node] = ebase + excl;
        dinv[node] = rsqrtf((float)(v + 1));  // +1 self-loop
    }
    __syncthreads();
    for (int e = ebase + t; e < eend; e += 256) {
        uint2 p = pairs[e];
        int pos = atomicAdd(&lcur[p.y & 255], 1);
        csr_src[pos] = (int)p.x;
    }
}

// ============ W transpose + hi/lo bf16 split ============
__global__ __launch_bounds__(256) void wsplit(const float* __restrict__ W,
                                              unsigned short* __restrict__ Th,
                                              unsigned short* __restrict__ Tl,
                                              int K, int logM) {
    int i = blockIdx.x * 256 + threadIdx.x;
    int M = 1 << logM;
    if (i >= K * M) return;
    int k = i >> logM;
    int n = i & (M - 1);
    float v = W[i];
    unsigned short h = f2bf(v);
    float r = v - bf2f(h);
    Th[(size_t)n * K + k] = h;
    Tl[(size_t)n * K + k] = f2bf(r);
}

// ============ MFMA GEMM: dbuf LDS-staged A (bf16 hi/lo), B in regs, bf16 out ============
template <int K, int M>
__global__ __launch_bounds__(M * 4) void gemm_mfma_v3(const float* __restrict__ A,
                                                      const unsigned short* __restrict__ Bth,
                                                      const unsigned short* __restrict__ Btl,
                                                      const float* __restrict__ dinv,
                                                      unsigned short* __restrict__ Cb, int N) {
    const int KS = K / 32;
    const int THREADS = M * 4;
    const int CPT = 512 / THREADS;
    const int PL = 64 * 40;

    __shared__ __align__(16) unsigned short Ah[2 * PL];
    __shared__ __align__(16) unsigned short Al[2 * PL];

    const int tid = threadIdx.x;
    const int wave = tid >> 6;
    const int lane = tid & 63;
    const int n16 = lane & 15;
    const int quad = lane >> 4;
    const int row0 = blockIdx.x * 64;

    bf16x8 bh[KS], bl[KS];
    {
        const size_t brow = (size_t)(wave * 16 + n16) * K + quad * 8;
#pragma unroll
        for (int ks = 0; ks < KS; ks++) {
            bh[ks] = *(const bf16x8*)(Bth + brow + ks * 32);
            bl[ks] = *(const bf16x8*)(Btl + brow + ks * 32);
        }
    }

    int srow[CPT], sc4[CPT];
    const float* aptr[CPT];
#pragma unroll
    for (int p = 0; p < CPT; p++) {
        int q = p * THREADS + tid;
        srow[p] = q >> 3;
        sc4[p] = q & 7;
        int grow = row0 + srow[p];
        if (grow >= N) grow = N - 1;
        aptr[p] = A + (size_t)grow * K + sc4[p] * 4;
    }

    float4 pre[CPT];
#pragma unroll
    for (int p = 0; p < CPT; p++) pre[p] = *(const float4*)(aptr[p]);

#pragma unroll
    for (int p = 0; p < CPT; p++) {
        ushort4 h4, l4;
        unsigned short* hp = (unsigned short*)&h4;
        unsigned short* lp = (unsigned short*)&l4;
        float av[4] = {pre[p].x, pre[p].y, pre[p].z, pre[p].w};
#pragma unroll
        for (int j = 0; j < 4; j++) {
            unsigned short h = f2bf(av[j]);
            hp[j] = h;
            lp[j] = f2bf(av[j] - bf2f(h));
        }
        *(ushort4*)(Ah + srow[p] * 40 + sc4[p] * 4) = h4;
        *(ushort4*)(Al + srow[p] * 40 + sc4[p] * 4) = l4;
    }
    if (KS > 1) {
#pragma unroll
        for (int p = 0; p < CPT; p++) pre[p] = *(const float4*)(aptr[p] + 32);
    }
    __syncthreads();

    f32x4 acc[4] = {};

#pragma unroll
    for (int ks = 0; ks < KS; ks++) {
        const int cur = (ks & 1) * PL;
#pragma unroll
        for (int rt = 0; rt < 4; rt++) {
            const int ro = cur + (rt * 16 + n16) * 40 + quad * 8;
            bf16x8 ah = *(const bf16x8*)(Ah + ro);
            bf16x8 al = *(const bf16x8*)(Al + ro);
            acc[rt] = __builtin_amdgcn_mfma_f32_16x16x32_bf16(ah, bh[ks], acc[rt], 0, 0, 0);
            acc[rt] = __builtin_amdgcn_mfma_f32_16x16x32_bf16(ah, bl[ks], acc[rt], 0, 0, 0);
            acc[rt] = __builtin_amdgcn_mfma_f32_16x16x32_bf16(al, bh[ks], acc[rt], 0, 0, 0);
        }
        if (ks + 1 < KS) {
            const int nxt = ((ks + 1) & 1) * PL;
#pragma unroll
            for (int p = 0; p < CPT; p++) {
                ushort4 h4, l4;
                unsigned short* hp = (unsigned short*)&h4;
                unsigned short* lp = (unsigned short*)&l4;
                float av[4] = {pre[p].x, pre[p].y, pre[p].z, pre[p].w};
#pragma unroll
                for (int j = 0; j < 4; j++) {
                    unsigned short h = f2bf(av[j]);
                    hp[j] = h;
                    lp[j] = f2bf(av[j] - bf2f(h));
                }
                *(ushort4*)(Ah + nxt + srow[p] * 40 + sc4[p] * 4) = h4;
                *(ushort4*)(Al + nxt + srow[p] * 40 + sc4[p] * 4) = l4;
            }
            if (ks + 2 < KS) {
#pragma unroll
                for (int p = 0; p < CPT; p++)
                    pre[p] = *(const float4*)(aptr[p] + (ks + 2) * 32);
            }
        }
        __syncthreads();
    }

#pragma unroll
    for (int rt = 0; rt < 4; rt++) {
        const int orow_base = row0 + rt * 16 + quad * 4;
#pragma unroll
        for (int r = 0; r < 4; r++) {
            int orow = orow_base + r;
            if (orow < N) {
                Cb[(size_t)orow * M + wave * 16 + n16] = f2bf(dinv[orow] * acc[rt][r]);
            }
        }
    }
}

// ============ fused gather-aggregate (bf16 rows) + epilogue (fp32 out) ============
template <bool RELU, int M>
__global__ __launch_bounds__(256) void gather_agg_bf(const unsigned short* __restrict__ hnb,
                                                     const int* __restrict__ rowptr,
                                                     const int* __restrict__ csr_src,
                                                     const float* __restrict__ dinv,
                                                     const float* __restrict__ bias,
                                                     float* __restrict__ outp, int n) {
    const int MQ = M / 8;
    const int GPB = 256 / MQ;
    int g = blockIdx.x * GPB + threadIdx.x / MQ;
    int j = threadIdx.x % MQ;
    if (g >= n) return;

    float acc[8] = {};
    {
        bf16x8 v = *(const bf16x8*)(hnb + (size_t)g * M + j * 8);  // self-loop
#pragma unroll
        for (int i = 0; i < 8; i++) acc[i] = bf2f((unsigned short)v[i]);
    }

    int e = rowptr[g];
    const int end = rowptr[g + 1];
    for (; e + 3 < end; e += 4) {
        int s0 = csr_src[e];
        int s1 = csr_src[e + 1];
        int s2 = csr_src[e + 2];
        int s3 = csr_src[e + 3];
        bf16x8 v0 = *(const bf16x8*)(hnb + (size_t)s0 * M + j * 8);
        bf16x8 v1 = *(const bf16x8*)(hnb + (size_t)s1 * M + j * 8);
        bf16x8 v2 = *(const bf16x8*)(hnb + (size_t)s2 * M + j * 8);
        bf16x8 v3 = *(const bf16x8*)(hnb + (size_t)s3 * M + j * 8);
#pragma unroll
        for (int i = 0; i < 8; i++) {
            acc[i] += (bf2f((unsigned short)v0[i]) + bf2f((unsigned short)v1[i])) +
                      (bf2f((unsigned short)v2[i]) + bf2f((unsigned short)v3[i]));
        }
    }
    for (; e < end; e++) {
        int s0 = csr_src[e];
        bf16x8 v0 = *(const bf16x8*)(hnb + (size_t)s0 * M + j * 8);
#pragma unroll
        for (int i = 0; i < 8; i++) acc[i] += bf2f((unsigned short)v0[i]);
    }

    const float s = dinv[g];
    float r[8];
#pragma unroll
    for (int i = 0; i < 8; i++) {
        r[i] = s * acc[i] + bias[j * 8 + i];
        if (RELU) r[i] = fmaxf(r[i], 0.0f);
    }
    float* op = outp + (size_t)g * M + j * 8;
    *(float4*)(op) = make_float4(r[0], r[1], r[2], r[3]);
    *(float4*)(op + 4) = make_float4(r[4], r[5], r[6], r[7]);
}

extern "C" void kernel_launch(void* const* d_in, const int* in_sizes, int n_in,
                              void* d_out, int out_size, void* d_ws, size_t ws_size,
                              hipStream_t stream) {
    const float* x  = (const float*)d_in[0];
    const int*   ei = (const int*)d_in[1];
    const float* W1 = (const float*)d_in[2];
    const float* b1 = (const float*)d_in[3];
    const float* W2 = (const float*)d_in[4];
    const float* b2 = (const float*)d_in[5];

    const int N = N_NODES;
    const int E = in_sizes[1] / 2;
    const int* src = ei;
    const int* dst = ei + E;

    char* ws = (char*)d_ws;
    size_t off = 0;
    auto carve = [&](size_t bytes) {
        char* p = ws + off;
        off += (bytes + 255) & ~(size_t)255;
        return p;
    };
    int*   cnt     = (int*)  carve((size_t)NCH * NBKT * 4);
    int*   offm    = (int*)  carve((size_t)NCH * NBKT * 4);
    int*   total   = (int*)  carve((size_t)NBKT * 4);
    int*   bbase   = (int*)  carve((size_t)(NBKT + 1) * 4);
    uint2* pairs   = (uint2*)carve((size_t)E * 8);
    int*   rowptr  = (int*)  carve((size_t)(N + 1) * 4);
    int*   csr_src = (int*)  carve((size_t)E * 4);
    float* dinv    = (float*)carve((size_t)N * 4);
    unsigned short* W1th = (unsigned short*)carve((size_t)256 * 128 * 2);
    unsigned short* W1tl = (unsigned short*)carve((size_t)256 * 128 * 2);
    unsigned short* W2th = (unsigned short*)carve((size_t)128 * 64 * 2);
    unsigned short* W2tl = (unsigned short*)carve((size_t)128 * 64 * 2);
    unsigned short* hn1b = (unsigned short*)carve((size_t)N * 128 * 2);
    float*          h1   = (float*)carve((size_t)N * 128 * 4);
    unsigned short* hn2b = hn1b;  // hn1b dead after gather1

    const int epc = (E + NCH - 1) / NCH;
    const int nbk = (N + 255) >> 8;  // 196 live buckets

    // ---- CSR build (bucketed counting sort, zero global atomics) ----
    bkt_count<<<NCH, 256, 0, stream>>>(dst, cnt, E, epc);
    bkt_scan_chunks<<<NBKT, 256, 0, stream>>>(cnt, offm, total);
    bkt_scan_base<<<1, 256, 0, stream>>>(total, bbase, rowptr, N, E);
    bkt_scatter<<<NCH, 256, 0, stream>>>(src, dst, offm, bbase, pairs, E, epc);
    bkt_csr<<<nbk, 256, 0, stream>>>(pairs, bbase, rowptr, csr_src, dinv, N);

    // ---- weight transpose + split (tiny) ----
    wsplit<<<(256 * 128 + 255) / 256, 256, 0, stream>>>(W1, W1th, W1tl, 256, 7);
    wsplit<<<(128 * 64 + 255) / 256, 256, 0, stream>>>(W2, W2th, W2tl, 128, 6);

    const int GB = (N + 63) / 64;  // 782 blocks

    // ---- layer 1 ----
    gemm_mfma_v3<256, 128><<<GB, 512, 0, stream>>>(x, W1th, W1tl, dinv, hn1b, N);
    {
        const int GPB = 256 / (128 / 8);  // 16 nodes/block
        gather_agg_bf<true, 128><<<(N + GPB - 1) / GPB, 256, 0, stream>>>(
            hn1b, rowptr, csr_src, dinv, b1, h1, N);
    }

    // ---- layer 2 ----
    gemm_mfma_v3<128, 64><<<GB, 256, 0, stream>>>(h1, W2th, W2tl, dinv, hn2b, N);
    {
        const int GPB = 256 / (64 / 8);  // 32 nodes/block
        gather_agg_bf<false, 64><<<(N + GPB - 1) / GPB, 256, 0, stream>>>(
            hn2b, rowptr, csr_src, dinv, b2, (float*)d_out, N);
    }
}

// Round 7
// 206.058 us; speedup vs baseline: 11.1172x; 1.0304x over previous
//
#include <hip/hip_runtime.h>

#define N_NODES 50000
#define NCH 1024         // edge chunks (blocks in B1/B2)
#define NBKT 256         // bucket slots (dst>>8; 196 live for N=50000)

typedef short bf16x8 __attribute__((ext_vector_type(8)));
typedef float f32x4 __attribute__((ext_vector_type(4)));

__device__ inline unsigned short f2bf(float f) {
    union { float f; unsigned u; } v; v.f = f;
    unsigned u = v.u;
    unsigned lsb = (u >> 16) & 1u;
    u += 0x7fffu + lsb;  // round-to-nearest-even
    return (unsigned short)(u >> 16);
}

__device__ inline float bf2f(unsigned short h) {
    union { unsigned u; float f; } v; v.u = ((unsigned)h) << 16;
    return v.f;
}

// ============ bucketed counting-sort CSR build (no global atomics) ============

// B1: per-chunk bucket histogram -> cnt[c][b]
__global__ __launch_bounds__(256) void bkt_count(const int* __restrict__ dst,
                                                 int* __restrict__ cnt, int E, int epc) {
    __shared__ int h[NBKT];
    h[threadIdx.x] = 0;
    __syncthreads();
    const int c = blockIdx.x;
    const int e0 = c * epc;
    const int e1 = min(E, e0 + epc);
    for (int e = e0 + threadIdx.x; e < e1; e += 256)
        atomicAdd(&h[dst[e] >> 8], 1);
    __syncthreads();
    cnt[c * NBKT + threadIdx.x] = h[threadIdx.x];
}

// S1: per-bucket exclusive scan over 1024 chunks (4/thread); off[c][b], total[b]
__global__ __launch_bounds__(256) void bkt_scan_chunks(const int* __restrict__ cnt,
                                                       int* __restrict__ off,
                                                       int* __restrict__ total) {
    __shared__ int sh[256];
    const int b = blockIdx.x;
    const int t = threadIdx.x;
    int v[4], pre[4];
    int s = 0;
#pragma unroll
    for (int i = 0; i < 4; i++) {
        v[i] = cnt[(t * 4 + i) * NBKT + b];
        pre[i] = s;
        s += v[i];
    }
    sh[t] = s;
    __syncthreads();
    for (int o = 1; o < 256; o <<= 1) {
        int u = (t >= o) ? sh[t - o] : 0;
        __syncthreads();
        sh[t] += u;
        __syncthreads();
    }
    const int base = sh[t] - s;
#pragma unroll
    for (int i = 0; i < 4; i++) off[(t * 4 + i) * NBKT + b] = base + pre[i];
    if (t == 255) total[b] = sh[255];
}

// S2: scan totals -> bbase[0..256]; rowptr[N]=E
__global__ __launch_bounds__(256) void bkt_scan_base(const int* __restrict__ total,
                                                     int* __restrict__ bbase,
                                                     int* __restrict__ rowptr,
                                                     int N, int E) {
    __shared__ int sh[256];
    const int t = threadIdx.x;
    int v = total[t];
    sh[t] = v;
    __syncthreads();
    for (int o = 1; o < 256; o <<= 1) {
        int u = (t >= o) ? sh[t - o] : 0;
        __syncthreads();
        sh[t] += u;
        __syncthreads();
    }
    bbase[t] = sh[t] - v;
    if (t == 255) bbase[256] = sh[255];
    if (t == 0) rowptr[N] = E;
}

// B2: scatter packed (src<<8 | dst&255) into bucket-sorted order; LDS cursors
__global__ __launch_bounds__(256) void bkt_scatter(const int* __restrict__ src,
                                                   const int* __restrict__ dst,
                                                   const int* __restrict__ off,
                                                   const int* __restrict__ bbase,
                                                   unsigned* __restrict__ pairs,
                                                   int E, int epc) {
    __shared__ int cur[NBKT];
    const int c = blockIdx.x;
    cur[threadIdx.x] = bbase[threadIdx.x] + off[c * NBKT + threadIdx.x];
    __syncthreads();
    const int e0 = c * epc;
    const int e1 = min(E, e0 + epc);
    for (int e = e0 + threadIdx.x; e < e1; e += 256) {
        int s = src[e];
        int d = dst[e];
        int pos = atomicAdd(&cur[d >> 8], 1);
        pairs[pos] = ((unsigned)s << 8) | (unsigned)(d & 255);
    }
}

// B3: per-bucket local CSR: rowptr, dinv, csr_src (dense regional writes)
__global__ __launch_bounds__(256) void bkt_csr(const unsigned* __restrict__ pairs,
                                               const int* __restrict__ bbase,
                                               int* __restrict__ rowptr,
                                               int* __restrict__ csr_src,
                                               float* __restrict__ dinv, int N) {
    __shared__ int lh[256];
    __shared__ int sc[256];
    __shared__ int lcur[256];
    const int b = blockIdx.x;
    const int t = threadIdx.x;
    const int ebase = bbase[b];
    const int eend = bbase[b + 1];
    const int node0 = b << 8;

    lh[t] = 0;
    __syncthreads();
    for (int e = ebase + t; e < eend; e += 256)
        atomicAdd(&lh[pairs[e] & 255u], 1);
    __syncthreads();
    int v = lh[t];
    sc[t] = v;
    __syncthreads();
    for (int o = 1; o < 256; o <<= 1) {
        int u = (t >= o) ? sc[t - o] : 0;
        __syncthreads();
        sc[t] += u;
        __syncthreads();
    }
    const int excl = sc[t] - v;
    lcur[t] = ebase + excl;
    const int node = node0 + t;
    if (node < N) {
        rowptr[node] = ebase + excl;
        dinv[node] = rsqrtf((float)(v + 1));  // +1 self-loop
    }
    __syncthreads();
    for (int e = ebase + t; e < eend; e += 256) {
        unsigned p = pairs[e];
        int pos = atomicAdd(&lcur[p & 255u], 1);
        csr_src[pos] = (int)(p >> 8);
    }
}

// ============ merged W split into MFMA-fragment order ============
// Bf[((g*KS+ks)*64 + quad*16 + n16)*8 + j] = bf16 of W^T[col=g*16+n16][k=ks*32+quad*8+j]
__global__ __launch_bounds__(256) void wsplit_frag(const float* __restrict__ W1,
                                                   const float* __restrict__ W2,
                                                   unsigned short* __restrict__ B1h,
                                                   unsigned short* __restrict__ B1l,
                                                   unsigned short* __restrict__ B2h,
                                                   unsigned short* __restrict__ B2l) {
    int i = blockIdx.x * 256 + threadIdx.x;
    const float* W;
    unsigned short *Th, *Tl;
    int K, logM, idx;
    if (i < 32768) { W = W1; Th = B1h; Tl = B1l; K = 256; logM = 7; idx = i; }
    else if (i < 32768 + 8192) { W = W2; Th = B2h; Tl = B2l; K = 128; logM = 6; idx = i - 32768; }
    else return;
    const int M = 1 << logM;
    const int KS = K / 32;
    int k = idx >> logM;
    int n = idx & (M - 1);
    float v = W[idx];
    unsigned short h = f2bf(v);
    unsigned short l = f2bf(v - bf2f(h));
    int g = n >> 4, n16 = n & 15, ks = k >> 5, quad = (k >> 3) & 3, j = k & 7;
    size_t o = ((size_t)((g * KS + ks) * 64 + quad * 16 + n16)) * 8 + j;
    Th[o] = h;
    Tl[o] = l;
}

// ============ MFMA GEMM v4: 32x32 patch/wave, rolling B, dbuf LDS A ============
// Cb[r,c] = bf16( dinv[r] * sum_k A[r,k]*B[k,c] ).
// Block: 64 rows x M cols; waves = (64/32)*(M/32); wave -> (rpair, cpair).
template <int K, int M>
__global__ __launch_bounds__(M * 4) void gemm_mfma_v4(const float* __restrict__ A,
                                                      const unsigned short* __restrict__ Bfh,
                                                      const unsigned short* __restrict__ Bfl,
                                                      const float* __restrict__ dinv,
                                                      unsigned short* __restrict__ Cb, int N) {
    const int KS = K / 32;
    const int THREADS = M * 4;
    const int CPT = 512 / THREADS;
    const int PL = 64 * 40;
    const int CPAIRS = M / 32;

    __shared__ __align__(16) unsigned short Ah[2 * PL];
    __shared__ __align__(16) unsigned short Al[2 * PL];

    const int tid = threadIdx.x;
    const int wave = tid >> 6;
    const int lane = tid & 63;
    const int n16 = lane & 15;
    const int quad = lane >> 4;
    const int cpair = wave & (CPAIRS - 1);
    const int rpair = wave / CPAIRS;  // 0 or 1
    const int row0 = blockIdx.x * 64;

    // rolling B fragments: [parity][ct]
    bf16x8 bh[2][2], bl[2][2];
    auto loadB = [&](int ks, int par) {
#pragma unroll
        for (int ct = 0; ct < 2; ct++) {
            const int g = cpair * 2 + ct;
            const size_t o = ((size_t)(g * KS + ks) * 64 + lane) * 8;
            bh[par][ct] = *(const bf16x8*)(Bfh + o);
            bl[par][ct] = *(const bf16x8*)(Bfl + o);
        }
    };
    loadB(0, 0);

    // A staging (64 x 32 fp32 tile = 512 float4 chunks)
    int srow[CPT], sc4[CPT];
    const float* aptr[CPT];
#pragma unroll
    for (int p = 0; p < CPT; p++) {
        int q = p * THREADS + tid;
        srow[p] = q >> 3;
        sc4[p] = q & 7;
        int grow = row0 + srow[p];
        if (grow >= N) grow = N - 1;
        aptr[p] = A + (size_t)grow * K + sc4[p] * 4;
    }

    float4 pre[CPT];
#pragma unroll
    for (int p = 0; p < CPT; p++) pre[p] = *(const float4*)(aptr[p]);

#pragma unroll
    for (int p = 0; p < CPT; p++) {
        ushort4 h4, l4;
        unsigned short* hp = (unsigned short*)&h4;
        unsigned short* lp = (unsigned short*)&l4;
        float av[4] = {pre[p].x, pre[p].y, pre[p].z, pre[p].w};
#pragma unroll
        for (int j = 0; j < 4; j++) {
            unsigned short h = f2bf(av[j]);
            hp[j] = h;
            lp[j] = f2bf(av[j] - bf2f(h));
        }
        *(ushort4*)(Ah + srow[p] * 40 + sc4[p] * 4) = h4;
        *(ushort4*)(Al + srow[p] * 40 + sc4[p] * 4) = l4;
    }
    if (KS > 1) {
#pragma unroll
        for (int p = 0; p < CPT; p++) pre[p] = *(const float4*)(aptr[p] + 32);
    }
    __syncthreads();

    f32x4 acc[2][2] = {};

#pragma unroll
    for (int ks = 0; ks < KS; ks++) {
        const int cur = ks & 1;
        if (ks + 1 < KS) loadB(ks + 1, cur ^ 1);
        // compute from current LDS buffer
#pragma unroll
        for (int rt = 0; rt < 2; rt++) {
            const int ro = cur * PL + (rpair * 32 + rt * 16 + n16) * 40 + quad * 8;
            bf16x8 ah = *(const bf16x8*)(Ah + ro);
            bf16x8 al = *(const bf16x8*)(Al + ro);
#pragma unroll
            for (int ct = 0; ct < 2; ct++) {
                acc[rt][ct] = __builtin_amdgcn_mfma_f32_16x16x32_bf16(ah, bh[cur][ct], acc[rt][ct], 0, 0, 0);
                acc[rt][ct] = __builtin_amdgcn_mfma_f32_16x16x32_bf16(ah, bl[cur][ct], acc[rt][ct], 0, 0, 0);
                acc[rt][ct] = __builtin_amdgcn_mfma_f32_16x16x32_bf16(al, bh[cur][ct], acc[rt][ct], 0, 0, 0);
            }
        }
        // stage next A tile into other buffer; prefetch tile after
        if (ks + 1 < KS) {
            const int nxt = (cur ^ 1) * PL;
#pragma unroll
            for (int p = 0; p < CPT; p++) {
                ushort4 h4, l4;
                unsigned short* hp = (unsigned short*)&h4;
                unsigned short* lp = (unsigned short*)&l4;
                float av[4] = {pre[p].x, pre[p].y, pre[p].z, pre[p].w};
#pragma unroll
                for (int j = 0; j < 4; j++) {
                    unsigned short h = f2bf(av[j]);
                    hp[j] = h;
                    lp[j] = f2bf(av[j] - bf2f(h));
                }
                *(ushort4*)(Ah + nxt + srow[p] * 40 + sc4[p] * 4) = h4;
                *(ushort4*)(Al + nxt + srow[p] * 40 + sc4[p] * 4) = l4;
            }
            if (ks + 2 < KS) {
#pragma unroll
                for (int p = 0; p < CPT; p++)
                    pre[p] = *(const float4*)(aptr[p] + (ks + 2) * 32);
            }
        }
        __syncthreads();
    }

    // epilogue: per 16x16 tile, D mapping col = lane&15, row = quad*4 + reg
#pragma unroll
    for (int rt = 0; rt < 2; rt++) {
#pragma unroll
        for (int ct = 0; ct < 2; ct++) {
            const int col = cpair * 32 + ct * 16 + n16;
            const int rbase = row0 + rpair * 32 + rt * 16 + quad * 4;
#pragma unroll
            for (int r = 0; r < 4; r++) {
                int orow = rbase + r;
                if (orow < N) {
                    Cb[(size_t)orow * M + col] = f2bf(dinv[orow] * acc[rt][ct][r]);
                }
            }
        }
    }
}

// ============ fused gather-aggregate (bf16 rows) + epilogue (fp32 out) ============
template <bool RELU, int M>
__global__ __launch_bounds__(256) void gather_agg_bf(const unsigned short* __restrict__ hnb,
                                                     const int* __restrict__ rowptr,
                                                     const int* __restrict__ csr_src,
                                                     const float* __restrict__ dinv,
                                                     const float* __restrict__ bias,
                                                     float* __restrict__ outp, int n) {
    const int MQ = M / 8;
    const int GPB = 256 / MQ;
    int g = blockIdx.x * GPB + threadIdx.x / MQ;
    int j = threadIdx.x % MQ;
    if (g >= n) return;

    float acc[8] = {};
    {
        bf16x8 v = *(const bf16x8*)(hnb + (size_t)g * M + j * 8);  // self-loop
#pragma unroll
        for (int i = 0; i < 8; i++) acc[i] = bf2f((unsigned short)v[i]);
    }

    int e = rowptr[g];
    const int end = rowptr[g + 1];
    for (; e + 3 < end; e += 4) {
        int s0 = csr_src[e];
        int s1 = csr_src[e + 1];
        int s2 = csr_src[e + 2];
        int s3 = csr_src[e + 3];
        bf16x8 v0 = *(const bf16x8*)(hnb + (size_t)s0 * M + j * 8);
        bf16x8 v1 = *(const bf16x8*)(hnb + (size_t)s1 * M + j * 8);
        bf16x8 v2 = *(const bf16x8*)(hnb + (size_t)s2 * M + j * 8);
        bf16x8 v3 = *(const bf16x8*)(hnb + (size_t)s3 * M + j * 8);
#pragma unroll
        for (int i = 0; i < 8; i++) {
            acc[i] += (bf2f((unsigned short)v0[i]) + bf2f((unsigned short)v1[i])) +
                      (bf2f((unsigned short)v2[i]) + bf2f((unsigned short)v3[i]));
        }
    }
    for (; e < end; e++) {
        int s0 = csr_src[e];
        bf16x8 v0 = *(const bf16x8*)(hnb + (size_t)s0 * M + j * 8);
#pragma unroll
        for (int i = 0; i < 8; i++) acc[i] += bf2f((unsigned short)v0[i]);
    }

    const float s = dinv[g];
    float r[8];
#pragma unroll
    for (int i = 0; i < 8; i++) {
        r[i] = s * acc[i] + bias[j * 8 + i];
        if (RELU) r[i] = fmaxf(r[i], 0.0f);
    }
    float* op = outp + (size_t)g * M + j * 8;
    *(float4*)(op) = make_float4(r[0], r[1], r[2], r[3]);
    *(float4*)(op + 4) = make_float4(r[4], r[5], r[6], r[7]);
}

extern "C" void kernel_launch(void* const* d_in, const int* in_sizes, int n_in,
                              void* d_out, int out_size, void* d_ws, size_t ws_size,
                              hipStream_t stream) {
    const float* x  = (const float*)d_in[0];
    const int*   ei = (const int*)d_in[1];
    const float* W1 = (const float*)d_in[2];
    const float* b1 = (const float*)d_in[3];
    const float* W2 = (const float*)d_in[4];
    const float* b2 = (const float*)d_in[5];

    const int N = N_NODES;
    const int E = in_sizes[1] / 2;
    const int* src = ei;
    const int* dst = ei + E;

    char* ws = (char*)d_ws;
    size_t off = 0;
    auto carve = [&](size_t bytes) {
        char* p = ws + off;
        off += (bytes + 255) & ~(size_t)255;
        return p;
    };
    int*      cnt     = (int*)     carve((size_t)NCH * NBKT * 4);
    int*      offm    = (int*)     carve((size_t)NCH * NBKT * 4);
    int*      total   = (int*)     carve((size_t)NBKT * 4);
    int*      bbase   = (int*)     carve((size_t)(NBKT + 1) * 4);
    unsigned* pairs   = (unsigned*)carve((size_t)E * 4);
    int*      rowptr  = (int*)     carve((size_t)(N + 1) * 4);
    int*      csr_src = (int*)     carve((size_t)E * 4);
    float*    dinv    = (float*)   carve((size_t)N * 4);
    unsigned short* W1th = (unsigned short*)carve((size_t)256 * 128 * 2);
    unsigned short* W1tl = (unsigned short*)carve((size_t)256 * 128 * 2);
    unsigned short* W2th = (unsigned short*)carve((size_t)128 * 64 * 2);
    unsigned short* W2tl = (unsigned short*)carve((size_t)128 * 64 * 2);
    unsigned short* hn1b = (unsigned short*)carve((size_t)N * 128 * 2);
    float*          h1   = (float*)carve((size_t)N * 128 * 4);
    unsigned short* hn2b = hn1b;  // hn1b dead after gather1

    const int epc = (E + NCH - 1) / NCH;
    const int nbk = (N + 255) >> 8;  // 196 live buckets

    // ---- CSR build (bucketed counting sort, zero global atomics) ----
    bkt_count<<<NCH, 256, 0, stream>>>(dst, cnt, E, epc);
    bkt_scan_chunks<<<NBKT, 256, 0, stream>>>(cnt, offm, total);
    bkt_scan_base<<<1, 256, 0, stream>>>(total, bbase, rowptr, N, E);
    bkt_scatter<<<NCH, 256, 0, stream>>>(src, dst, offm, bbase, pairs, E, epc);
    bkt_csr<<<nbk, 256, 0, stream>>>(pairs, bbase, rowptr, csr_src, dinv, N);

    // ---- merged weight split into fragment order ----
    wsplit_frag<<<160, 256, 0, stream>>>(W1, W2, W1th, W1tl, W2th, W2tl);

    const int GB = (N + 63) / 64;  // 782 blocks

    // ---- layer 1 ----
    gemm_mfma_v4<256, 128><<<GB, 512, 0, stream>>>(x, W1th, W1tl, dinv, hn1b, N);
    {
        const int GPB = 256 / (128 / 8);  // 16 nodes/block
        gather_agg_bf<true, 128><<<(N + GPB - 1) / GPB, 256, 0, stream>>>(
            hn1b, rowptr, csr_src, dinv, b1, h1, N);
    }

    // ---- layer 2 ----
    gemm_mfma_v4<128, 64><<<GB, 256, 0, stream>>>(h1, W2th, W2tl, dinv, hn2b, N);
    {
        const int GPB = 256 / (64 / 8);  // 32 nodes/block
        gather_agg_bf<false, 64><<<(N + GPB - 1) / GPB, 256, 0, stream>>>(
            hn2b, rowptr, csr_src, dinv, b2, (float*)d_out, N);
    }
}